// Round 2
// baseline (2205.990 us; speedup 1.0000x reference)
//
#include <hip/hip_runtime.h>
#include <hip/hip_bf16.h>

#define B_  4
#define S_  2048
#define D_  1024
#define H_  16
#define DH_ 64
#define M_  (B_*S_)   // 8192

// ---------------- GEMM: C[M,1024] = A[M,1024] @ W[1024,1024] + bias ----------
// 128x128 tile, BK=16, 256 threads, 8x8 register tile per thread. fp32.
__global__ __launch_bounds__(256)
void gemm_bias(const float* __restrict__ A, const float* __restrict__ W,
               const float* __restrict__ bias, float* __restrict__ C)
{
    __shared__ float As[16][128];   // [k][m]
    __shared__ float Bs[16][128];   // [k][n]
    const int t  = threadIdx.x;
    const int tr = t >> 4;          // 0..15
    const int tc = t & 15;          // 0..15
    const int m0 = blockIdx.x * 128;
    const int n0 = blockIdx.y * 128;

    const int la_r = t >> 2;        // 0..63
    const int la_c = (t & 3) * 4;   // 0,4,8,12
    const int lb_r = t >> 5;        // 0..7
    const int lb_c = (t & 31) * 4;  // 0..124

    float acc[8][8] = {};

    for (int k0 = 0; k0 < 1024; k0 += 16) {
        float4 a0 = *(const float4*)(A + (size_t)(m0 + la_r)      * D_ + k0 + la_c);
        float4 a1 = *(const float4*)(A + (size_t)(m0 + la_r + 64) * D_ + k0 + la_c);
        float4 w0 = *(const float4*)(W + (size_t)(k0 + lb_r)      * D_ + n0 + lb_c);
        float4 w1 = *(const float4*)(W + (size_t)(k0 + lb_r + 8)  * D_ + n0 + lb_c);
        __syncthreads();   // previous iteration's readers done
        As[la_c+0][la_r]    = a0.x; As[la_c+1][la_r]    = a0.y;
        As[la_c+2][la_r]    = a0.z; As[la_c+3][la_r]    = a0.w;
        As[la_c+0][la_r+64] = a1.x; As[la_c+1][la_r+64] = a1.y;
        As[la_c+2][la_r+64] = a1.z; As[la_c+3][la_r+64] = a1.w;
        *(float4*)(&Bs[lb_r][lb_c])   = w0;
        *(float4*)(&Bs[lb_r+8][lb_c]) = w1;
        __syncthreads();
        #pragma unroll
        for (int kk = 0; kk < 16; ++kk) {
            float a[8], b[8];
            *(float4*)(a)   = *(const float4*)(&As[kk][tr*8]);
            *(float4*)(a+4) = *(const float4*)(&As[kk][tr*8+4]);
            *(float4*)(b)   = *(const float4*)(&Bs[kk][tc*8]);
            *(float4*)(b+4) = *(const float4*)(&Bs[kk][tc*8+4]);
            #pragma unroll
            for (int i = 0; i < 8; ++i)
                #pragma unroll
                for (int j = 0; j < 8; ++j)
                    acc[i][j] += a[i] * b[j];
        }
    }
    #pragma unroll
    for (int i = 0; i < 8; ++i) {
        const size_t m = (size_t)(m0 + tr*8 + i);
        #pragma unroll
        for (int j = 0; j < 8; ++j) {
            const int n = n0 + tc*8 + j;
            C[m * D_ + n] = acc[i][j] + bias[n];
        }
    }
}

// ---------------- QK^T + exp (unnormalized, fp32) + rowsum -------------------
// One block per (b, h, 64 q-rows). Writes exp(q.k/8) fp32 to attn region,
// full row-sums to ws.
__global__ __launch_bounds__(256)
void qk_exp(const float* __restrict__ Q, const float* __restrict__ K,
            float* __restrict__ attn, float* __restrict__ rowsum)
{
    const int qb = blockIdx.x, h = blockIdx.y, b = blockIdx.z;
    const int s0 = qb * 64;
    const int t  = threadIdx.x;
    const int tq = t >> 4, tk = t & 15;

    __shared__ float Qt[64][68];    // [d][q] transposed
    __shared__ float Kt[64][68];    // [d][k] transposed
    __shared__ float red[64][17];

    #pragma unroll
    for (int l = 0; l < 4; ++l) {
        const int f  = t + 256*l;
        const int qq = f >> 4;
        const int d4 = (f & 15) * 4;
        float4 vv = *(const float4*)(Q + ((size_t)(b*S_ + s0 + qq))*D_ + h*DH_ + d4);
        Qt[d4+0][qq] = vv.x; Qt[d4+1][qq] = vv.y;
        Qt[d4+2][qq] = vv.z; Qt[d4+3][qq] = vv.w;
    }

    float psum[4] = {0.f, 0.f, 0.f, 0.f};
    const size_t abase = ((size_t)(b*H_ + h)*S_ + s0) * S_;

    for (int kt = 0; kt < 32; ++kt) {
        __syncthreads();   // Kt readers from prev iter done (also publishes Qt on kt=0)
        #pragma unroll
        for (int l = 0; l < 4; ++l) {
            const int f  = t + 256*l;
            const int kk = f >> 4;
            const int d4 = (f & 15) * 4;
            float4 vv = *(const float4*)(K + ((size_t)(b*S_ + kt*64 + kk))*D_ + h*DH_ + d4);
            Kt[d4+0][kk] = vv.x; Kt[d4+1][kk] = vv.y;
            Kt[d4+2][kk] = vv.z; Kt[d4+3][kk] = vv.w;
        }
        __syncthreads();

        float acc[4][4] = {};
        #pragma unroll 8
        for (int d = 0; d < 64; ++d) {
            float4 av = *(const float4*)(&Qt[d][tq*4]);
            float4 bv = *(const float4*)(&Kt[d][tk*4]);
            const float a[4] = {av.x, av.y, av.z, av.w};
            const float bb[4] = {bv.x, bv.y, bv.z, bv.w};
            #pragma unroll
            for (int i = 0; i < 4; ++i)
                #pragma unroll
                for (int j = 0; j < 4; ++j)
                    acc[i][j] += a[i] * bb[j];
        }

        #pragma unroll
        for (int i = 0; i < 4; ++i) {
            float4 e;
            e.x = expf(acc[i][0] * 0.125f);
            e.y = expf(acc[i][1] * 0.125f);
            e.z = expf(acc[i][2] * 0.125f);
            e.w = expf(acc[i][3] * 0.125f);
            psum[i] += (e.x + e.y) + (e.z + e.w);
            *(float4*)(attn + abase + (size_t)(tq*4 + i)*S_ + (size_t)(kt*64 + tk*4)) = e;
        }
    }

    #pragma unroll
    for (int i = 0; i < 4; ++i) red[tq*4+i][tk] = psum[i];
    __syncthreads();
    if (t < 64) {
        float s = 0.f;
        #pragma unroll
        for (int n = 0; n < 16; ++n) s += red[t][n];
        rowsum[(size_t)(b*H_ + h)*S_ + s0 + t] = s;
    }
}

// ---------------- PV + in-place attn normalization ---------------------------
// One block per (b, h, 64 q-rows). Reads unnormalized fp32 exp tiles, scales by
// 1/rowsum, writes normalized fp32 back to attn (block owns its rows), and
// accumulates ctx[b,s,h,dh] in fp32.
__global__ __launch_bounds__(256)
void pv_norm(float* __restrict__ attn, const float* __restrict__ V,
             const float* __restrict__ rowsum, float* __restrict__ ctx)
{
    const int qb = blockIdx.x, h = blockIdx.y, b = blockIdx.z;
    const int s0 = qb * 64;
    const int t  = threadIdx.x;
    const int tq = t >> 4, tk = t & 15;

    __shared__ float Et[64][68];    // [k][q] normalized attn tile (transposed)
    __shared__ float Vs[64][68];    // [k][dh]
    __shared__ float invs[64];

    const size_t rsbase = (size_t)(b*H_ + h)*S_ + s0;
    if (t < 64) invs[t] = 1.0f / rowsum[rsbase + t];
    const size_t abase = rsbase * S_;

    float acc[4][4] = {};

    for (int kt = 0; kt < 32; ++kt) {
        __syncthreads();   // prev readers done; publishes invs on kt=0
        #pragma unroll
        for (int l = 0; l < 4; ++l) {
            const int f  = t + 256*l;
            const int qq = f >> 4;          // 0..63
            const int c4 = (f & 15) * 4;    // 0..60
            const float inv = invs[qq];
            const size_t aidx = abase + (size_t)qq*S_ + (size_t)(kt*64 + c4);
            float4 raw = *(const float4*)(attn + aidx);
            raw.x *= inv; raw.y *= inv; raw.z *= inv; raw.w *= inv;
            *(float4*)(attn + aidx) = raw;          // normalized attn in place
            Et[c4+0][qq] = raw.x; Et[c4+1][qq] = raw.y;
            Et[c4+2][qq] = raw.z; Et[c4+3][qq] = raw.w;
        }
        #pragma unroll
        for (int l = 0; l < 4; ++l) {
            const int f  = t + 256*l;
            const int kk = f >> 4;
            const int d4 = (f & 15) * 4;
            float4 vv = *(const float4*)(V + ((size_t)(b*S_ + kt*64 + kk))*D_ + h*DH_ + d4);
            *(float4*)(&Vs[kk][d4]) = vv;
        }
        __syncthreads();

        #pragma unroll 8
        for (int kk = 0; kk < 64; ++kk) {
            float4 av = *(const float4*)(&Et[kk][tq*4]);
            float4 bv = *(const float4*)(&Vs[kk][tk*4]);
            const float a[4] = {av.x, av.y, av.z, av.w};
            const float bb[4] = {bv.x, bv.y, bv.z, bv.w};
            #pragma unroll
            for (int i = 0; i < 4; ++i)
                #pragma unroll
                for (int j = 0; j < 4; ++j)
                    acc[i][j] += a[i] * bb[j];
        }
    }

    #pragma unroll
    for (int i = 0; i < 4; ++i) {
        float4 o;
        o.x = acc[i][0]; o.y = acc[i][1]; o.z = acc[i][2]; o.w = acc[i][3];
        *(float4*)(ctx + ((size_t)(b*S_ + s0 + tq*4 + i))*D_ + h*DH_ + tk*4) = o;
    }
}

// ----------------------------------------------------------------------------
extern "C" void kernel_launch(void* const* d_in, const int* in_sizes, int n_in,
                              void* d_out, int out_size, void* d_ws, size_t ws_size,
                              hipStream_t stream)
{
    (void)in_sizes; (void)n_in; (void)out_size; (void)ws_size;
    const float* v  = (const float*)d_in[0];
    const float* k  = (const float*)d_in[1];
    const float* q  = (const float*)d_in[2];
    const float* Wq = (const float*)d_in[3];
    const float* bq = (const float*)d_in[4];
    const float* Wk = (const float*)d_in[5];
    const float* bk = (const float*)d_in[6];
    const float* Wv = (const float*)d_in[7];
    const float* bv = (const float*)d_in[8];
    const float* Wo = (const float*)d_in[9];
    const float* bo = (const float*)d_in[10];

    float* out  = (float*)d_out;                   // (B,S,D)   = 8,388,608 fp32
    float* attn = out + (size_t)M_ * D_;           // (B,H,S,S) = 268,435,456 fp32

    float* Qf   = (float*)d_ws;                    // 8M floats
    float* Kf   = Qf  + (size_t)M_ * D_;
    float* Vf   = Kf  + (size_t)M_ * D_;
    float* ctx  = Vf  + (size_t)M_ * D_;
    float* rsum = ctx + (size_t)M_ * D_;           // B*H*S floats

    dim3 bt(256);
    dim3 gg(64, 8);          // 8192/128 x 1024/128
    dim3 ga(32, 16, 4);      // S/64 x H x B

    gemm_bias<<<gg, bt, 0, stream>>>(q, Wq, bq, Qf);
    gemm_bias<<<gg, bt, 0, stream>>>(k, Wk, bk, Kf);
    gemm_bias<<<gg, bt, 0, stream>>>(v, Wv, bv, Vf);
    qk_exp  <<<ga, bt, 0, stream>>>(Qf, Kf, attn, rsum);
    pv_norm <<<ga, bt, 0, stream>>>(attn, Vf, rsum, ctx);
    gemm_bias<<<gg, bt, 0, stream>>>(ctx, Wo, bo, out);
}

// Round 3
// 1089.124 us; speedup vs baseline: 2.0255x; 2.0255x over previous
//
#include <hip/hip_runtime.h>
#include <hip/hip_bf16.h>

#define B_  4
#define S_  2048
#define D_  1024
#define H_  16
#define DH_ 64
#define M_  (B_*S_)   // 8192

typedef short bf16x8 __attribute__((ext_vector_type(8)));   // 8 bf16 = 4 VGPR
typedef float f32x4  __attribute__((ext_vector_type(4)));
typedef unsigned short u16;

__device__ __forceinline__ u16 f2b(float x) {
    union { __hip_bfloat16 h; u16 u; } c; c.h = __float2bfloat16(x); return c.u;
}

// ---------------- fp32 -> bf16 bulk convert ---------------------------------
__global__ __launch_bounds__(256)
void cvt_bf16(const float* __restrict__ in, u16* __restrict__ out, int n8)
{
    const int i = blockIdx.x*256 + threadIdx.x;
    if (i >= n8) return;
    float4 a = ((const float4*)in)[2*i];
    float4 b = ((const float4*)in)[2*i+1];
    union { u16 u[8]; uint4 v; } r;
    r.u[0]=f2b(a.x); r.u[1]=f2b(a.y); r.u[2]=f2b(a.z); r.u[3]=f2b(a.w);
    r.u[4]=f2b(b.x); r.u[5]=f2b(b.y); r.u[6]=f2b(b.z); r.u[7]=f2b(b.w);
    ((uint4*)out)[i] = r.v;
}

// ---------------- W[k][n] fp32 -> Wt[n][k] bf16 ------------------------------
__global__ __launch_bounds__(256)
void wtrans(const float* __restrict__ W, u16* __restrict__ Wt)
{
    __shared__ u16 Ts[64][80];     // [n][k], padded pitch (160B, 16B-aligned rows)
    const int t = threadIdx.x;
    const int k0 = blockIdx.x*64, n0 = blockIdx.y*64;
    const int kr = t >> 4, nc = (t & 15)*4;
    #pragma unroll
    for (int i = 0; i < 4; ++i) {
        const int kk = kr + i*16;
        float4 wv = *(const float4*)(W + (size_t)(k0 + kk)*D_ + n0 + nc);
        Ts[nc+0][kk] = f2b(wv.x); Ts[nc+1][kk] = f2b(wv.y);
        Ts[nc+2][kk] = f2b(wv.z); Ts[nc+3][kk] = f2b(wv.w);
    }
    __syncthreads();
    const int nr = t >> 2, kc = (t & 3)*16;
    u16* dst = Wt + (size_t)(n0 + nr)*D_ + k0 + kc;
    *(uint4*)(dst)     = *(const uint4*)(&Ts[nr][kc]);
    *(uint4*)(dst + 8) = *(const uint4*)(&Ts[nr][kc + 8]);
}

// ---------------- Vh[b,s,h*64+d] -> Vt[(b*H+h)*64+d][s] ----------------------
__global__ __launch_bounds__(256)
void vtrans(const u16* __restrict__ Vh, u16* __restrict__ Vt)
{
    __shared__ u16 Ts[64][80];     // [d][s]
    const int t = threadIdx.x;
    const int s0 = blockIdx.x*64, h = blockIdx.y, b = blockIdx.z;
    const int sr = t >> 2, dc = (t & 3)*16;
    const u16* src = Vh + (size_t)(b*S_ + s0 + sr)*D_ + h*DH_ + dc;
    u16 tmp[16];
    *(uint4*)(tmp)     = *(const uint4*)(src);
    *(uint4*)(tmp + 8) = *(const uint4*)(src + 8);
    #pragma unroll
    for (int i = 0; i < 16; ++i) Ts[dc + i][sr] = tmp[i];
    __syncthreads();
    const int dr = t >> 2, sc = (t & 3)*16;
    u16* dst = Vt + (size_t)((b*H_ + h)*DH_ + dr)*S_ + s0 + sc;
    *(uint4*)(dst)     = *(const uint4*)(&Ts[dr][sc]);
    *(uint4*)(dst + 8) = *(const uint4*)(&Ts[dr][sc + 8]);
}

// ---------------- bf16 MFMA GEMM: C[M][1024] = A@W + bias --------------------
// A[m][k] bf16, Wt[n][k] bf16. 128x128 tile, BK=64, 4 waves (2x2 of 64x64).
// LDS rows XOR-swizzled on 16B blocks -> 2-way conflicts (free).
template<bool F32OUT>
__global__ __launch_bounds__(256)
void gemm_bf16(const u16* __restrict__ Ab, const u16* __restrict__ Wt,
               const float* __restrict__ bias,
               u16* __restrict__ Cb, float* __restrict__ Cf)
{
    __shared__ u16 AsU[128*64];
    __shared__ u16 BsU[128*64];
    const int t = threadIdx.x;
    const int w = t >> 6, lane = t & 63;
    const int lo = lane & 15, g4 = lane >> 4;
    const int wr = w >> 1, wc = w & 1;
    const int m0 = blockIdx.x*128, n0 = blockIdx.y*128;

    const f32x4 zero = {0.f, 0.f, 0.f, 0.f};
    f32x4 acc[4][4];
    #pragma unroll
    for (int mi = 0; mi < 4; ++mi)
        #pragma unroll
        for (int ni = 0; ni < 4; ++ni) acc[mi][ni] = zero;

    bf16x8 ar[4], br[4];
    #pragma unroll
    for (int c = 0; c < 4; ++c) {
        const int idx = c*256 + t, row = idx >> 3, blk = idx & 7;
        ar[c] = *(const bf16x8*)(Ab + (size_t)(m0+row)*D_ + blk*8);
        br[c] = *(const bf16x8*)(Wt + (size_t)(n0+row)*D_ + blk*8);
    }

    for (int k0 = 0; k0 < 1024; k0 += 64) {
        __syncthreads();
        #pragma unroll
        for (int c = 0; c < 4; ++c) {
            const int idx = c*256 + t, row = idx >> 3, blk = idx & 7;
            *(bf16x8*)(AsU + row*64 + ((blk ^ (row&7))*8)) = ar[c];
            *(bf16x8*)(BsU + row*64 + ((blk ^ (row&7))*8)) = br[c];
        }
        __syncthreads();
        if (k0 + 64 < 1024) {
            #pragma unroll
            for (int c = 0; c < 4; ++c) {
                const int idx = c*256 + t, row = idx >> 3, blk = idx & 7;
                ar[c] = *(const bf16x8*)(Ab + (size_t)(m0+row)*D_ + k0 + 64 + blk*8);
                br[c] = *(const bf16x8*)(Wt + (size_t)(n0+row)*D_ + k0 + 64 + blk*8);
            }
        }
        #pragma unroll
        for (int ks = 0; ks < 2; ++ks) {
            bf16x8 af[4], bfr[4];
            #pragma unroll
            for (int mi = 0; mi < 4; ++mi) {
                const int row = wr*64 + mi*16 + lo;
                af[mi] = *(const bf16x8*)(AsU + row*64 + (((ks*4+g4) ^ (row&7))*8));
            }
            #pragma unroll
            for (int ni = 0; ni < 4; ++ni) {
                const int row = wc*64 + ni*16 + lo;
                bfr[ni] = *(const bf16x8*)(BsU + row*64 + (((ks*4+g4) ^ (row&7))*8));
            }
            #pragma unroll
            for (int mi = 0; mi < 4; ++mi)
                #pragma unroll
                for (int ni = 0; ni < 4; ++ni)
                    acc[mi][ni] = __builtin_amdgcn_mfma_f32_16x16x32_bf16(
                        af[mi], bfr[ni], acc[mi][ni], 0, 0, 0);
        }
    }

    #pragma unroll
    for (int ni = 0; ni < 4; ++ni) {
        const int n = n0 + wc*64 + ni*16 + lo;
        const float bb = bias[n];
        #pragma unroll
        for (int mi = 0; mi < 4; ++mi)
            #pragma unroll
            for (int j = 0; j < 4; ++j) {
                const size_t m = (size_t)(m0 + wr*64 + mi*16 + g4*4 + j);
                const float vv = acc[mi][ni][j] + bb;
                if constexpr (F32OUT) Cf[m*D_ + n] = vv;
                else                  Cb[m*D_ + n] = f2b(vv);
            }
    }
}

// ---------------- pass 1: ctx + rowsum (no attn I/O) -------------------------
// Block (qtile64, h, b); wave w owns 16 q-rows. QK^T via MFMA from global
// frags; exp; P -> per-wave swizzled LDS; PV via MFMA with Vt global frags.
__global__ __launch_bounds__(256)
void attn_ctx(const u16* __restrict__ Qh, const u16* __restrict__ Kh,
              const u16* __restrict__ Vt,
              u16* __restrict__ ctxb, float* __restrict__ rsum)
{
    __shared__ u16 Plds[4*16*64];   // per-wave 16q x 64key, XOR-swizzled
    const int t = threadIdx.x, w = t >> 6, lane = t & 63;
    const int lo = lane & 15, g4 = lane >> 4;
    const int q0 = blockIdx.x*64, h = blockIdx.y, b = blockIdx.z;
    const int qbase = q0 + w*16;
    u16* Pw = Plds + w*1024;

    bf16x8 qf[2];
    #pragma unroll
    for (int ks = 0; ks < 2; ++ks)
        qf[ks] = *(const bf16x8*)(Qh + (size_t)(b*S_ + qbase + lo)*D_ + h*DH_ + ks*32 + g4*8);

    size_t vtb[4];
    #pragma unroll
    for (int ni = 0; ni < 4; ++ni)
        vtb[ni] = (size_t)((b*H_ + h)*DH_ + ni*16 + lo)*S_;

    const f32x4 zero = {0.f, 0.f, 0.f, 0.f};
    f32x4 cacc[4];
    #pragma unroll
    for (int ni = 0; ni < 4; ++ni) cacc[ni] = zero;
    float rs[4] = {0.f, 0.f, 0.f, 0.f};

    for (int kt = 0; kt < 32; ++kt) {
        const size_t kbase = (size_t)(b*S_ + kt*64)*D_ + h*DH_;
        f32x4 sacc[4];
        #pragma unroll
        for (int ni = 0; ni < 4; ++ni) sacc[ni] = zero;
        #pragma unroll
        for (int ks = 0; ks < 2; ++ks)
            #pragma unroll
            for (int ni = 0; ni < 4; ++ni) {
                bf16x8 kf = *(const bf16x8*)(Kh + kbase + (size_t)(ni*16 + lo)*D_ + ks*32 + g4*8);
                sacc[ni] = __builtin_amdgcn_mfma_f32_16x16x32_bf16(qf[ks], kf, sacc[ni], 0, 0, 0);
            }
        #pragma unroll
        for (int ni = 0; ni < 4; ++ni)
            #pragma unroll
            for (int j = 0; j < 4; ++j) {
                const float p = __expf(sacc[ni][j] * 0.125f);
                rs[j] += p;
                const int row = g4*4 + j, key = ni*16 + lo;
                Pw[row*64 + (((key >> 3) ^ (row & 7))*8) + (key & 7)] = f2b(p);
            }
        asm volatile("" ::: "memory");   // order ds_writes before cross-lane reads
        #pragma unroll
        for (int ks = 0; ks < 2; ++ks) {
            const bf16x8 pa = *(const bf16x8*)(Pw + lo*64 + (((ks*4 + g4) ^ (lo & 7))*8));
            #pragma unroll
            for (int ni = 0; ni < 4; ++ni) {
                const bf16x8 vf = *(const bf16x8*)(Vt + vtb[ni] + kt*64 + ks*32 + g4*8);
                cacc[ni] = __builtin_amdgcn_mfma_f32_16x16x32_bf16(pa, vf, cacc[ni], 0, 0, 0);
            }
        }
        asm volatile("" ::: "memory");   // keep next iter's writes after these reads
    }

    #pragma unroll
    for (int j = 0; j < 4; ++j) {
        float r = rs[j];
        r += __shfl_xor(r, 1); r += __shfl_xor(r, 2);
        r += __shfl_xor(r, 4); r += __shfl_xor(r, 8);
        rs[j] = r;
    }
    const size_t rb = (size_t)(b*H_ + h)*S_ + qbase;
    if (lo == 0) {
        #pragma unroll
        for (int j = 0; j < 4; ++j) rsum[rb + g4*4 + j] = rs[j];
    }
    #pragma unroll
    for (int j = 0; j < 4; ++j) {
        const float inv = 1.0f / rs[j];
        #pragma unroll
        for (int ni = 0; ni < 4; ++ni)
            ctxb[(size_t)(b*S_ + qbase + g4*4 + j)*D_ + h*DH_ + ni*16 + lo] =
                f2b(cacc[ni][j] * inv);
    }
}

// ---------------- pass 2: recompute QK^T, write normalized attn --------------
__global__ __launch_bounds__(256)
void attn_write(const u16* __restrict__ Qh, const u16* __restrict__ Kh,
                const float* __restrict__ rsum, float* __restrict__ attn)
{
    const int t = threadIdx.x, w = t >> 6, lane = t & 63;
    const int lo = lane & 15, g4 = lane >> 4;
    const int q0 = blockIdx.x*64, h = blockIdx.y, b = blockIdx.z;
    const int qbase = q0 + w*16;

    bf16x8 qf[2];
    #pragma unroll
    for (int ks = 0; ks < 2; ++ks)
        qf[ks] = *(const bf16x8*)(Qh + (size_t)(b*S_ + qbase + lo)*D_ + h*DH_ + ks*32 + g4*8);

    const size_t rb = (size_t)(b*H_ + h)*S_ + qbase;
    float invj[4];
    #pragma unroll
    for (int j = 0; j < 4; ++j) invj[j] = 1.0f / rsum[rb + g4*4 + j];

    const f32x4 zero = {0.f, 0.f, 0.f, 0.f};
    const size_t abase = (size_t)(b*H_ + h)*S_*S_;

    for (int kt = 0; kt < 32; ++kt) {
        const size_t kbase = (size_t)(b*S_ + kt*64)*D_ + h*DH_;
        f32x4 sacc[4];
        #pragma unroll
        for (int ni = 0; ni < 4; ++ni) sacc[ni] = zero;
        #pragma unroll
        for (int ks = 0; ks < 2; ++ks)
            #pragma unroll
            for (int ni = 0; ni < 4; ++ni) {
                bf16x8 kf = *(const bf16x8*)(Kh + kbase + (size_t)(ni*16 + lo)*D_ + ks*32 + g4*8);
                sacc[ni] = __builtin_amdgcn_mfma_f32_16x16x32_bf16(qf[ks], kf, sacc[ni], 0, 0, 0);
            }
        #pragma unroll
        for (int ni = 0; ni < 4; ++ni)
            #pragma unroll
            for (int j = 0; j < 4; ++j) {
                const float p = __expf(sacc[ni][j] * 0.125f) * invj[j];
                attn[abase + (size_t)(qbase + g4*4 + j)*S_ + kt*64 + ni*16 + lo] = p;
            }
    }
}

// ----------------------------------------------------------------------------
extern "C" void kernel_launch(void* const* d_in, const int* in_sizes, int n_in,
                              void* d_out, int out_size, void* d_ws, size_t ws_size,
                              hipStream_t stream)
{
    (void)in_sizes; (void)n_in; (void)out_size; (void)ws_size;
    const float* v  = (const float*)d_in[0];
    const float* k  = (const float*)d_in[1];
    const float* q  = (const float*)d_in[2];
    const float* Wq = (const float*)d_in[3];
    const float* bq = (const float*)d_in[4];
    const float* Wk = (const float*)d_in[5];
    const float* bk = (const float*)d_in[6];
    const float* Wv = (const float*)d_in[7];
    const float* bv = (const float*)d_in[8];
    const float* Wo = (const float*)d_in[9];
    const float* bo = (const float*)d_in[10];

    float* out  = (float*)d_out;                  // (B,S,D) fp32
    float* attn = out + (size_t)M_*D_;            // (B,H,S,S) fp32

    u16* qb  = (u16*)d_ws;                        // bf16 input copies
    u16* kb  = qb  + (size_t)M_*D_;
    u16* vb  = kb  + (size_t)M_*D_;
    u16* Wqt = vb  + (size_t)M_*D_;               // transposed bf16 weights
    u16* Wkt = Wqt + (size_t)D_*D_;
    u16* Wvt = Wkt + (size_t)D_*D_;
    u16* Wot = Wvt + (size_t)D_*D_;
    u16* Qhb = Wot + (size_t)D_*D_;               // projected bf16
    u16* Khb = Qhb + (size_t)M_*D_;
    u16* Vhb = Khb + (size_t)M_*D_;
    u16* Vtb = Vhb + (size_t)M_*D_;               // V transposed per head
    u16* ctxb   = qb;                             // reuse (qb dead after q-proj)
    float* rsum = (float*)vb;                     // reuse (vb dead after v-proj)

    dim3 b256(256);
    dim3 gg(64, 8);
    dim3 ga(32, 16, 4);

    cvt_bf16<<<4096, b256, 0, stream>>>(q, qb, M_*D_/8);
    cvt_bf16<<<4096, b256, 0, stream>>>(k, kb, M_*D_/8);
    cvt_bf16<<<4096, b256, 0, stream>>>(v, vb, M_*D_/8);
    wtrans<<<dim3(16,16), b256, 0, stream>>>(Wq, Wqt);
    wtrans<<<dim3(16,16), b256, 0, stream>>>(Wk, Wkt);
    wtrans<<<dim3(16,16), b256, 0, stream>>>(Wv, Wvt);
    wtrans<<<dim3(16,16), b256, 0, stream>>>(Wo, Wot);
    gemm_bf16<false><<<gg, b256, 0, stream>>>(qb, Wqt, bq, Qhb, nullptr);
    gemm_bf16<false><<<gg, b256, 0, stream>>>(kb, Wkt, bk, Khb, nullptr);
    gemm_bf16<false><<<gg, b256, 0, stream>>>(vb, Wvt, bv, Vhb, nullptr);
    vtrans<<<ga, b256, 0, stream>>>(Vhb, Vtb);
    attn_ctx<<<ga, b256, 0, stream>>>(Qhb, Khb, Vtb, ctxb, rsum);
    attn_write<<<ga, b256, 0, stream>>>(Qhb, Khb, rsum, attn);
    gemm_bf16<true><<<gg, b256, 0, stream>>>(ctxb, Wot, bo, nullptr, out);
}

// Round 4
// 866.465 us; speedup vs baseline: 2.5460x; 1.2570x over previous
//
#include <hip/hip_runtime.h>
#include <hip/hip_bf16.h>

#define B_  4
#define S_  2048
#define D_  1024
#define H_  16
#define DH_ 64
#define M_  (B_*S_)   // 8192

typedef short bf16x8 __attribute__((ext_vector_type(8)));   // 8 bf16 = 4 VGPR
typedef float f32x4  __attribute__((ext_vector_type(4)));
typedef unsigned short u16;

__device__ __forceinline__ u16 f2b(float x) {
    union { __hip_bfloat16 h; u16 u; } c; c.h = __float2bfloat16(x); return c.u;
}

// global -> LDS direct (16B per lane). lds dst must be wave-uniform base;
// HW adds lane*16. Global src is per-lane (pre-swizzle goes here).
__device__ __forceinline__ void gl_lds16(const u16* g, u16* l) {
    __builtin_amdgcn_global_load_lds(
        (const __attribute__((address_space(1))) unsigned int*)g,
        (__attribute__((address_space(3))) unsigned int*)l,
        16, 0, 0);
}

// ---------------- fp32 -> bf16 bulk convert ---------------------------------
__global__ __launch_bounds__(256)
void cvt_bf16(const float* __restrict__ in, u16* __restrict__ out, int n8)
{
    const int i = blockIdx.x*256 + threadIdx.x;
    if (i >= n8) return;
    float4 a = ((const float4*)in)[2*i];
    float4 b = ((const float4*)in)[2*i+1];
    union { u16 u[8]; uint4 v; } r;
    r.u[0]=f2b(a.x); r.u[1]=f2b(a.y); r.u[2]=f2b(a.z); r.u[3]=f2b(a.w);
    r.u[4]=f2b(b.x); r.u[5]=f2b(b.y); r.u[6]=f2b(b.z); r.u[7]=f2b(b.w);
    ((uint4*)out)[i] = r.v;
}

// ---------------- W[k][n] fp32 -> Wt[n][k] bf16 ------------------------------
__global__ __launch_bounds__(256)
void wtrans(const float* __restrict__ W, u16* __restrict__ Wt)
{
    __shared__ u16 Ts[64][80];
    const int t = threadIdx.x;
    const int k0 = blockIdx.x*64, n0 = blockIdx.y*64;
    const int kr = t >> 4, nc = (t & 15)*4;
    #pragma unroll
    for (int i = 0; i < 4; ++i) {
        const int kk = kr + i*16;
        float4 wv = *(const float4*)(W + (size_t)(k0 + kk)*D_ + n0 + nc);
        Ts[nc+0][kk] = f2b(wv.x); Ts[nc+1][kk] = f2b(wv.y);
        Ts[nc+2][kk] = f2b(wv.z); Ts[nc+3][kk] = f2b(wv.w);
    }
    __syncthreads();
    const int nr = t >> 2, kc = (t & 3)*16;
    u16* dst = Wt + (size_t)(n0 + nr)*D_ + k0 + kc;
    *(uint4*)(dst)     = *(const uint4*)(&Ts[nr][kc]);
    *(uint4*)(dst + 8) = *(const uint4*)(&Ts[nr][kc + 8]);
}

// ---------------- Vh[b,s,h*64+d] -> Vt[(b*H+h)*64+d][s] ----------------------
__global__ __launch_bounds__(256)
void vtrans(const u16* __restrict__ Vh, u16* __restrict__ Vt)
{
    __shared__ u16 Ts[64][80];
    const int t = threadIdx.x;
    const int s0 = blockIdx.x*64, h = blockIdx.y, b = blockIdx.z;
    const int sr = t >> 2, dc = (t & 3)*16;
    const u16* src = Vh + (size_t)(b*S_ + s0 + sr)*D_ + h*DH_ + dc;
    u16 tmp[16];
    *(uint4*)(tmp)     = *(const uint4*)(src);
    *(uint4*)(tmp + 8) = *(const uint4*)(src + 8);
    #pragma unroll
    for (int i = 0; i < 16; ++i) Ts[dc + i][sr] = tmp[i];
    __syncthreads();
    const int dr = t >> 2, sc = (t & 3)*16;
    u16* dst = Vt + (size_t)((b*H_ + h)*DH_ + dr)*S_ + s0 + sc;
    *(uint4*)(dst)     = *(const uint4*)(&Ts[dr][sc]);
    *(uint4*)(dst + 8) = *(const uint4*)(&Ts[dr][sc + 8]);
}

// ---------------- bf16 MFMA GEMM: C[M][1024] = A@W + bias --------------------
// 128x128 tile, BK=64, 4 waves (2x2 of 64x64). Staging via global_load_lds
// (16B/lane); XOR-swizzle applied on the global SOURCE address and the LDS
// read (LDS itself linear, per rule #21 / m173).
template<bool F32OUT>
__global__ __launch_bounds__(256)
void gemm_bf16(const u16* __restrict__ Ab, const u16* __restrict__ Wt,
               const float* __restrict__ bias,
               u16* __restrict__ Cb, float* __restrict__ Cf)
{
    __shared__ u16 AsU[128*64];   // [row][8 chunks of 8 bf16], chunk pre-swizzled
    __shared__ u16 BsU[128*64];
    const int t = threadIdx.x;
    const int w = t >> 6, lane = t & 63;
    const int lo = lane & 15, g4 = lane >> 4;
    const int wr = w >> 1, wc = w & 1;
    const int m0 = blockIdx.x*128, n0 = blockIdx.y*128;
    const int wbase = w*64;

    const f32x4 zero = {0.f, 0.f, 0.f, 0.f};
    f32x4 acc[4][4];
    #pragma unroll
    for (int mi = 0; mi < 4; ++mi)
        #pragma unroll
        for (int ni = 0; ni < 4; ++ni) acc[mi][ni] = zero;

    for (int k0 = 0; k0 < 1024; k0 += 64) {
        __syncthreads();   // prev compute's ds_reads done
        #pragma unroll
        for (int c = 0; c < 4; ++c) {
            const int idx = c*256 + wbase + lane;        // slot 0..1023
            const int row = idx >> 3;
            const int gblk = (idx & 7) ^ (row & 7);      // pre-swizzled source
            gl_lds16(Ab + (size_t)(m0+row)*D_ + k0 + gblk*8, AsU + (size_t)(c*256 + wbase)*8);
            gl_lds16(Wt + (size_t)(n0+row)*D_ + k0 + gblk*8, BsU + (size_t)(c*256 + wbase)*8);
        }
        __syncthreads();   // vmcnt drained, LDS visible
        #pragma unroll
        for (int ks = 0; ks < 2; ++ks) {
            bf16x8 af[4], bfr[4];
            #pragma unroll
            for (int mi = 0; mi < 4; ++mi) {
                const int row = wr*64 + mi*16 + lo;
                af[mi] = *(const bf16x8*)(AsU + row*64 + (((ks*4+g4) ^ (lo&7))*8));
            }
            #pragma unroll
            for (int ni = 0; ni < 4; ++ni) {
                const int row = wc*64 + ni*16 + lo;
                bfr[ni] = *(const bf16x8*)(BsU + row*64 + (((ks*4+g4) ^ (lo&7))*8));
            }
            #pragma unroll
            for (int mi = 0; mi < 4; ++mi)
                #pragma unroll
                for (int ni = 0; ni < 4; ++ni)
                    acc[mi][ni] = __builtin_amdgcn_mfma_f32_16x16x32_bf16(
                        af[mi], bfr[ni], acc[mi][ni], 0, 0, 0);
        }
    }

    #pragma unroll
    for (int ni = 0; ni < 4; ++ni) {
        const int n = n0 + wc*64 + ni*16 + lo;
        const float bb = bias[n];
        #pragma unroll
        for (int mi = 0; mi < 4; ++mi)
            #pragma unroll
            for (int j = 0; j < 4; ++j) {
                const size_t m = (size_t)(m0 + wr*64 + mi*16 + g4*4 + j);
                const float vv = acc[mi][ni][j] + bb;
                if constexpr (F32OUT) Cf[m*D_ + n] = vv;
                else                  Cb[m*D_ + n] = f2b(vv);
            }
    }
}

// ---------------- pass 1: ctx + rowsum (no attn I/O) -------------------------
// Block = 128 q-rows (4 waves x 32 q). K/V tiles loaded once per kt per wave,
// shared across both 16-row q-blocks (2x arithmetic intensity vs round 3).
__global__ __launch_bounds__(256)
void attn_ctx(const u16* __restrict__ Qh, const u16* __restrict__ Kh,
              const u16* __restrict__ Vt,
              u16* __restrict__ ctxb, float* __restrict__ rsum)
{
    __shared__ u16 Plds[4*32*64];   // per-wave 32q x 64key, XOR-swizzled
    const int t = threadIdx.x, w = t >> 6, lane = t & 63;
    const int lo = lane & 15, g4 = lane >> 4;
    const int q0 = blockIdx.x*128, h = blockIdx.y, b = blockIdx.z;
    const int qbase = q0 + w*32;
    u16* Pw = Plds + w*2048;

    bf16x8 qf[2][2];
    #pragma unroll
    for (int qs = 0; qs < 2; ++qs)
        #pragma unroll
        for (int ks = 0; ks < 2; ++ks)
            qf[qs][ks] = *(const bf16x8*)(Qh + (size_t)(b*S_ + qbase + qs*16 + lo)*D_ + h*DH_ + ks*32 + g4*8);

    size_t vtb[4];
    #pragma unroll
    for (int ni = 0; ni < 4; ++ni)
        vtb[ni] = (size_t)((b*H_ + h)*DH_ + ni*16 + lo)*S_;

    const f32x4 zero = {0.f, 0.f, 0.f, 0.f};
    f32x4 cacc[2][4];
    #pragma unroll
    for (int qs = 0; qs < 2; ++qs)
        #pragma unroll
        for (int ni = 0; ni < 4; ++ni) cacc[qs][ni] = zero;
    float rs[2][4] = {};

    for (int kt = 0; kt < 32; ++kt) {
        const size_t kbase = (size_t)(b*S_ + kt*64)*D_ + h*DH_;
        f32x4 sacc[2][4];
        #pragma unroll
        for (int qs = 0; qs < 2; ++qs)
            #pragma unroll
            for (int ni = 0; ni < 4; ++ni) sacc[qs][ni] = zero;
        #pragma unroll
        for (int ks = 0; ks < 2; ++ks)
            #pragma unroll
            for (int ni = 0; ni < 4; ++ni) {
                const bf16x8 kf = *(const bf16x8*)(Kh + kbase + (size_t)(ni*16 + lo)*D_ + ks*32 + g4*8);
                sacc[0][ni] = __builtin_amdgcn_mfma_f32_16x16x32_bf16(qf[0][ks], kf, sacc[0][ni], 0, 0, 0);
                sacc[1][ni] = __builtin_amdgcn_mfma_f32_16x16x32_bf16(qf[1][ks], kf, sacc[1][ni], 0, 0, 0);
            }
        #pragma unroll
        for (int qs = 0; qs < 2; ++qs)
            #pragma unroll
            for (int ni = 0; ni < 4; ++ni)
                #pragma unroll
                for (int j = 0; j < 4; ++j) {
                    const float p = __expf(sacc[qs][ni][j] * 0.125f);
                    rs[qs][j] += p;
                    const int row = qs*16 + g4*4 + j, key = ni*16 + lo;
                    Pw[row*64 + (((key >> 3) ^ (row & 7))*8) + (key & 7)] = f2b(p);
                }
        asm volatile("" ::: "memory");
        #pragma unroll
        for (int ks = 0; ks < 2; ++ks) {
            bf16x8 vf[4];
            #pragma unroll
            for (int ni = 0; ni < 4; ++ni)
                vf[ni] = *(const bf16x8*)(Vt + vtb[ni] + kt*64 + ks*32 + g4*8);
            #pragma unroll
            for (int qs = 0; qs < 2; ++qs) {
                const int prow = qs*16 + lo;
                const bf16x8 pa = *(const bf16x8*)(Pw + prow*64 + (((ks*4 + g4) ^ (lo & 7))*8));
                #pragma unroll
                for (int ni = 0; ni < 4; ++ni)
                    cacc[qs][ni] = __builtin_amdgcn_mfma_f32_16x16x32_bf16(pa, vf[ni], cacc[qs][ni], 0, 0, 0);
            }
        }
        asm volatile("" ::: "memory");
    }

    #pragma unroll
    for (int qs = 0; qs < 2; ++qs) {
        #pragma unroll
        for (int j = 0; j < 4; ++j) {
            float r = rs[qs][j];
            r += __shfl_xor(r, 1); r += __shfl_xor(r, 2);
            r += __shfl_xor(r, 4); r += __shfl_xor(r, 8);
            rs[qs][j] = r;
        }
        const size_t rb = (size_t)(b*H_ + h)*S_ + qbase + qs*16;
        if (lo == 0) {
            #pragma unroll
            for (int j = 0; j < 4; ++j) rsum[rb + g4*4 + j] = rs[qs][j];
        }
        #pragma unroll
        for (int j = 0; j < 4; ++j) {
            const float inv = 1.0f / rs[qs][j];
            #pragma unroll
            for (int ni = 0; ni < 4; ++ni)
                ctxb[(size_t)(b*S_ + qbase + qs*16 + g4*4 + j)*D_ + h*DH_ + ni*16 + lo] =
                    f2b(cacc[qs][ni][j] * inv);
        }
    }
}

// ---------------- pass 2: recompute QK^T (swapped), write normalized attn ----
// mfma(K,Q) gives C[k,q]: each lane holds 4 consecutive k for one q ->
// float4 stores along the attn row. Bitwise-identical exp args vs pass 1.
__global__ __launch_bounds__(256)
void attn_write(const u16* __restrict__ Qh, const u16* __restrict__ Kh,
                const float* __restrict__ rsum, float* __restrict__ attn)
{
    const int t = threadIdx.x, w = t >> 6, lane = t & 63;
    const int lo = lane & 15, g4 = lane >> 4;
    const int q0 = blockIdx.x*64, h = blockIdx.y, b = blockIdx.z;
    const int qbase = q0 + w*16;

    bf16x8 qf[2];
    #pragma unroll
    for (int ks = 0; ks < 2; ++ks)
        qf[ks] = *(const bf16x8*)(Qh + (size_t)(b*S_ + qbase + lo)*D_ + h*DH_ + ks*32 + g4*8);

    const float inv = 1.0f / rsum[(size_t)(b*H_ + h)*S_ + qbase + lo];

    const f32x4 zero = {0.f, 0.f, 0.f, 0.f};
    float* arow = attn + (size_t)(b*H_ + h)*S_*S_ + (size_t)(qbase + lo)*S_;

    for (int kt = 0; kt < 32; ++kt) {
        const size_t kbase = (size_t)(b*S_ + kt*64)*D_ + h*DH_;
        f32x4 sacc[4];
        #pragma unroll
        for (int ni = 0; ni < 4; ++ni) sacc[ni] = zero;
        #pragma unroll
        for (int ks = 0; ks < 2; ++ks)
            #pragma unroll
            for (int ni = 0; ni < 4; ++ni) {
                const bf16x8 kf = *(const bf16x8*)(Kh + kbase + (size_t)(ni*16 + lo)*D_ + ks*32 + g4*8);
                sacc[ni] = __builtin_amdgcn_mfma_f32_16x16x32_bf16(kf, qf[ks], sacc[ni], 0, 0, 0);
            }
        #pragma unroll
        for (int ni = 0; ni < 4; ++ni) {
            float4 p;
            p.x = __expf(sacc[ni][0] * 0.125f) * inv;
            p.y = __expf(sacc[ni][1] * 0.125f) * inv;
            p.z = __expf(sacc[ni][2] * 0.125f) * inv;
            p.w = __expf(sacc[ni][3] * 0.125f) * inv;
            *(float4*)(arow + kt*64 + ni*16 + g4*4) = p;
        }
    }
}

// ----------------------------------------------------------------------------
extern "C" void kernel_launch(void* const* d_in, const int* in_sizes, int n_in,
                              void* d_out, int out_size, void* d_ws, size_t ws_size,
                              hipStream_t stream)
{
    (void)in_sizes; (void)n_in; (void)out_size; (void)ws_size;
    const float* v  = (const float*)d_in[0];
    const float* k  = (const float*)d_in[1];
    const float* q  = (const float*)d_in[2];
    const float* Wq = (const float*)d_in[3];
    const float* bq = (const float*)d_in[4];
    const float* Wk = (const float*)d_in[5];
    const float* bk = (const float*)d_in[6];
    const float* Wv = (const float*)d_in[7];
    const float* bv = (const float*)d_in[8];
    const float* Wo = (const float*)d_in[9];
    const float* bo = (const float*)d_in[10];

    float* out  = (float*)d_out;                  // (B,S,D) fp32
    float* attn = out + (size_t)M_*D_;            // (B,H,S,S) fp32

    u16* qb  = (u16*)d_ws;
    u16* kb  = qb  + (size_t)M_*D_;
    u16* vb  = kb  + (size_t)M_*D_;
    u16* Wqt = vb  + (size_t)M_*D_;
    u16* Wkt = Wqt + (size_t)D_*D_;
    u16* Wvt = Wkt + (size_t)D_*D_;
    u16* Wot = Wvt + (size_t)D_*D_;
    u16* Qhb = Wot + (size_t)D_*D_;
    u16* Khb = Qhb + (size_t)M_*D_;
    u16* Vhb = Khb + (size_t)M_*D_;
    u16* Vtb = Vhb + (size_t)M_*D_;
    u16* ctxb   = qb;                             // reuse (dead after q-proj)
    float* rsum = (float*)vb;                     // reuse (dead after v-proj)

    dim3 b256(256);
    dim3 gg(64, 8);
    dim3 gc(16, 16, 4);      // attn_ctx: 128 q-rows per block
    dim3 gw(32, 16, 4);      // attn_write: 64 q-rows per block

    cvt_bf16<<<4096, b256, 0, stream>>>(q, qb, M_*D_/8);
    cvt_bf16<<<4096, b256, 0, stream>>>(k, kb, M_*D_/8);
    cvt_bf16<<<4096, b256, 0, stream>>>(v, vb, M_*D_/8);
    wtrans<<<dim3(16,16), b256, 0, stream>>>(Wq, Wqt);
    wtrans<<<dim3(16,16), b256, 0, stream>>>(Wk, Wkt);
    wtrans<<<dim3(16,16), b256, 0, stream>>>(Wv, Wvt);
    wtrans<<<dim3(16,16), b256, 0, stream>>>(Wo, Wot);
    gemm_bf16<false><<<gg, b256, 0, stream>>>(qb, Wqt, bq, Qhb, nullptr);
    gemm_bf16<false><<<gg, b256, 0, stream>>>(kb, Wkt, bk, Khb, nullptr);
    gemm_bf16<false><<<gg, b256, 0, stream>>>(vb, Wvt, bv, Vhb, nullptr);
    vtrans<<<dim3(32,16,4), b256, 0, stream>>>(Vhb, Vtb);
    attn_ctx<<<gc, b256, 0, stream>>>(Qhb, Khb, Vtb, ctxb, rsum);
    attn_write<<<gw, b256, 0, stream>>>(Qhb, Khb, rsum, attn);
    gemm_bf16<true><<<gg, b256, 0, stream>>>(ctxb, Wot, bo, nullptr, out);
}

// Round 6
// 667.688 us; speedup vs baseline: 3.3039x; 1.2977x over previous
//
#include <hip/hip_runtime.h>
#include <hip/hip_bf16.h>

#define B_  4
#define S_  2048
#define D_  1024
#define H_  16
#define DH_ 64
#define M_  (B_*S_)   // 8192

typedef short bf16x8 __attribute__((ext_vector_type(8)));   // 8 bf16 = 4 VGPR
typedef float f32x4  __attribute__((ext_vector_type(4)));
typedef unsigned short u16;

__device__ __forceinline__ u16 f2b(float x) {
    union { __hip_bfloat16 h; u16 u; } c; c.h = __float2bfloat16(x); return c.u;
}

// global -> LDS direct (16B per lane). LDS dst is wave-uniform base + lane*16;
// global src is per-lane (pre-swizzle applied there, rule #21/m173).
__device__ __forceinline__ void gl_lds16(const u16* g, u16* l) {
    __builtin_amdgcn_global_load_lds(
        (const __attribute__((address_space(1))) unsigned int*)g,
        (__attribute__((address_space(3))) unsigned int*)l,
        16, 0, 0);
}

// ---------------- fp32 -> bf16 bulk convert, q/k/v in one launch -------------
__global__ __launch_bounds__(256)
void cvt3(const float* __restrict__ q, const float* __restrict__ k,
          const float* __restrict__ v,
          u16* __restrict__ qb, u16* __restrict__ kb, u16* __restrict__ vb)
{
    const float* src = blockIdx.y == 0 ? q : (blockIdx.y == 1 ? k : v);
    u16*         dst = blockIdx.y == 0 ? qb : (blockIdx.y == 1 ? kb : vb);
    const int i = blockIdx.x*256 + threadIdx.x;      // 0..2^20-1 exact
    float4 a = ((const float4*)src)[2*i];
    float4 b = ((const float4*)src)[2*i+1];
    union { u16 u[8]; uint4 v4; } r;
    r.u[0]=f2b(a.x); r.u[1]=f2b(a.y); r.u[2]=f2b(a.z); r.u[3]=f2b(a.w);
    r.u[4]=f2b(b.x); r.u[5]=f2b(b.y); r.u[6]=f2b(b.z); r.u[7]=f2b(b.w);
    ((uint4*)dst)[i] = r.v4;
}

// ---------------- W[k][n] fp32 -> Wt[n][k] bf16, all four in one launch ------
__global__ __launch_bounds__(256)
void wtrans4(const float* __restrict__ Wq, const float* __restrict__ Wk,
             const float* __restrict__ Wv, const float* __restrict__ Wo,
             u16* __restrict__ Wqt, u16* __restrict__ Wkt,
             u16* __restrict__ Wvt, u16* __restrict__ Wot)
{
    const int z = blockIdx.z;
    const float* W  = z==0 ? Wq  : (z==1 ? Wk  : (z==2 ? Wv  : Wo));
    u16*         Wt = z==0 ? Wqt : (z==1 ? Wkt : (z==2 ? Wvt : Wot));
    __shared__ u16 Ts[64][80];
    const int t = threadIdx.x;
    const int k0 = blockIdx.x*64, n0 = blockIdx.y*64;
    const int kr = t >> 4, nc = (t & 15)*4;
    #pragma unroll
    for (int i = 0; i < 4; ++i) {
        const int kk = kr + i*16;
        float4 wv = *(const float4*)(W + (size_t)(k0 + kk)*D_ + n0 + nc);
        Ts[nc+0][kk] = f2b(wv.x); Ts[nc+1][kk] = f2b(wv.y);
        Ts[nc+2][kk] = f2b(wv.z); Ts[nc+3][kk] = f2b(wv.w);
    }
    __syncthreads();
    const int nr = t >> 2, kc = (t & 3)*16;
    u16* dst = Wt + (size_t)(n0 + nr)*D_ + k0 + kc;
    *(uint4*)(dst)     = *(const uint4*)(&Ts[nr][kc]);
    *(uint4*)(dst + 8) = *(const uint4*)(&Ts[nr][kc + 8]);
}

// ---------------- QKV projection GEMM, one launch (z selects) ----------------
// 128x128 tile, BK=64, 4 waves. global_load_lds staging, pre-swizzled source.
// z=0 -> Qhb, z=1 -> Khb (row-major bf16); z=2 -> Vt transposed epilogue.
// XCD swizzle: each XCD owns an 8-wide m-slab (A 2MB + W 2MB L2-resident).
__global__ __launch_bounds__(256)
void proj_qkv(const u16* __restrict__ qb, const u16* __restrict__ kb,
              const u16* __restrict__ vb,
              const u16* __restrict__ Wqt, const u16* __restrict__ Wkt,
              const u16* __restrict__ Wvt,
              const float* __restrict__ bq, const float* __restrict__ bk,
              const float* __restrict__ bv,
              u16* __restrict__ Qhb, u16* __restrict__ Khb,
              u16* __restrict__ Vtb)
{
    const int z = blockIdx.z;
    const u16* Ab     = z==0 ? qb  : (z==1 ? kb  : vb);
    const u16* Wt     = z==0 ? Wqt : (z==1 ? Wkt : Wvt);
    const float* bias = z==0 ? bq  : (z==1 ? bk  : bv);

    const int lin = blockIdx.y*64 + blockIdx.x;      // 0..511
    const int cx = lin & 7, idx = lin >> 3;
    const int nx = cx*8 + (idx & 7), ny = idx >> 3;  // bijective
    const int m0 = nx*128, n0 = ny*128;

    __shared__ u16 AsU[128*64];
    __shared__ u16 BsU[128*64];
    const int t = threadIdx.x;
    const int w = t >> 6, lane = t & 63;
    const int lo = lane & 15, g4 = lane >> 4;
    const int wr = w >> 1, wc = w & 1;
    const int wbase = w*64;

    const f32x4 zero = {0.f, 0.f, 0.f, 0.f};
    f32x4 acc[4][4];
    #pragma unroll
    for (int mi = 0; mi < 4; ++mi)
        #pragma unroll
        for (int ni = 0; ni < 4; ++ni) acc[mi][ni] = zero;

    for (int k0 = 0; k0 < 1024; k0 += 64) {
        __syncthreads();
        #pragma unroll
        for (int c = 0; c < 4; ++c) {
            const int sidx = c*256 + wbase + lane;
            const int row = sidx >> 3;
            const int gblk = (sidx & 7) ^ (row & 7);
            gl_lds16(Ab + (size_t)(m0+row)*D_ + k0 + gblk*8, AsU + (size_t)(c*256 + wbase)*8);
            gl_lds16(Wt + (size_t)(n0+row)*D_ + k0 + gblk*8, BsU + (size_t)(c*256 + wbase)*8);
        }
        __syncthreads();
        #pragma unroll
        for (int ks = 0; ks < 2; ++ks) {
            bf16x8 af[4], bfr[4];
            #pragma unroll
            for (int mi = 0; mi < 4; ++mi) {
                const int row = wr*64 + mi*16 + lo;
                af[mi] = *(const bf16x8*)(AsU + row*64 + (((ks*4+g4) ^ (lo&7))*8));
            }
            #pragma unroll
            for (int ni = 0; ni < 4; ++ni) {
                const int row = wc*64 + ni*16 + lo;
                bfr[ni] = *(const bf16x8*)(BsU + row*64 + (((ks*4+g4) ^ (lo&7))*8));
            }
            #pragma unroll
            for (int mi = 0; mi < 4; ++mi)
                #pragma unroll
                for (int ni = 0; ni < 4; ++ni)
                    acc[mi][ni] = __builtin_amdgcn_mfma_f32_16x16x32_bf16(
                        af[mi], bfr[ni], acc[mi][ni], 0, 0, 0);
        }
    }

    if (z < 2) {
        u16* C = z==0 ? Qhb : Khb;
        #pragma unroll
        for (int ni = 0; ni < 4; ++ni) {
            const int n = n0 + wc*64 + ni*16 + lo;
            const float bb = bias[n];
            #pragma unroll
            for (int mi = 0; mi < 4; ++mi)
                #pragma unroll
                for (int j = 0; j < 4; ++j) {
                    const size_t m = (size_t)(m0 + wr*64 + mi*16 + g4*4 + j);
                    C[m*D_ + n] = f2b(acc[mi][ni][j] + bb);
                }
        }
    } else {
        // transposed: Vt[b*D_ + n][s], s = within-batch row
        const int bb_ = m0 >> 11;                        // batch (m0 mult of 128)
        const int sbase = (m0 & 2047) + wr*64;
        #pragma unroll
        for (int ni = 0; ni < 4; ++ni) {
            const int n = n0 + wc*64 + ni*16 + lo;
            const float bv_ = bias[n];
            u16* vrow = Vtb + (size_t)(bb_*D_ + n)*S_ + sbase;
            #pragma unroll
            for (int mi = 0; mi < 4; ++mi) {
                union { u16 u[4]; uint2 v2; } pk;
                #pragma unroll
                for (int j = 0; j < 4; ++j) pk.u[j] = f2b(acc[mi][ni][j] + bv_);
                *(uint2*)(vrow + mi*16 + g4*4) = pk.v2;  // 8B, aligned
            }
        }
    }
}

// ---------------- fused attention: ctx + rowsum, then attn write -------------
// Block = 128 q rows (4 waves x 32q), one (b,h). Phase A: QK^T->exp->P(LDS)
// ->PV (flash, no attn I/O), rowsums kept in LDS. Phase B: recompute QK^T
// swapped (C[k,q]) and nt-store normalized fp32 attn as f32x4 rows.
// XCD swizzle: 8 (b,h) pairs per XCD -> K/V (4MB) L2-resident.
__global__ __launch_bounds__(256)
void attn_fused(const u16* __restrict__ Qh, const u16* __restrict__ Kh,
                const u16* __restrict__ Vt,
                u16* __restrict__ ctxb, float* __restrict__ attn)
{
    __shared__ u16 Plds[4*2048];    // per-wave 32q x 64key, XOR-swizzled
    __shared__ float Rs[4][32];     // per-wave rowsums
    const int t = threadIdx.x, w = t >> 6, lane = t & 63;
    const int lo = lane & 15, g4 = lane >> 4;

    const int lin = (blockIdx.z*16 + blockIdx.y)*16 + blockIdx.x;  // 0..1023
    const int cx = lin & 7, idx = lin >> 3;
    const int nl = cx*128 + idx;                  // bijective chunked
    const int qb_ = nl & 15, bh = nl >> 4;
    const int h = bh & 15, b = bh >> 4;
    const int q0 = qb_*128;
    const int qbase = q0 + w*32;
    u16* Pw = Plds + w*2048;

    bf16x8 qf[2][2];
    #pragma unroll
    for (int qs = 0; qs < 2; ++qs)
        #pragma unroll
        for (int ks = 0; ks < 2; ++ks)
            qf[qs][ks] = *(const bf16x8*)(Qh + (size_t)(b*S_ + qbase + qs*16 + lo)*D_ + h*DH_ + ks*32 + g4*8);

    size_t vtb[4];
    #pragma unroll
    for (int ni = 0; ni < 4; ++ni)
        vtb[ni] = (size_t)(b*D_ + h*DH_ + ni*16 + lo)*S_;

    const f32x4 zero = {0.f, 0.f, 0.f, 0.f};
    f32x4 cacc[2][4];
    #pragma unroll
    for (int qs = 0; qs < 2; ++qs)
        #pragma unroll
        for (int ni = 0; ni < 4; ++ni) cacc[qs][ni] = zero;
    float rs[2][4] = {};

    // ---------------- phase A ----------------
    for (int kt = 0; kt < 32; ++kt) {
        const size_t kbase = (size_t)(b*S_ + kt*64)*D_ + h*DH_;
        f32x4 sacc[2][4];
        #pragma unroll
        for (int qs = 0; qs < 2; ++qs)
            #pragma unroll
            for (int ni = 0; ni < 4; ++ni) sacc[qs][ni] = zero;
        __builtin_amdgcn_s_setprio(1);
        #pragma unroll
        for (int ks = 0; ks < 2; ++ks)
            #pragma unroll
            for (int ni = 0; ni < 4; ++ni) {
                const bf16x8 kf = *(const bf16x8*)(Kh + kbase + (size_t)(ni*16 + lo)*D_ + ks*32 + g4*8);
                sacc[0][ni] = __builtin_amdgcn_mfma_f32_16x16x32_bf16(qf[0][ks], kf, sacc[0][ni], 0, 0, 0);
                sacc[1][ni] = __builtin_amdgcn_mfma_f32_16x16x32_bf16(qf[1][ks], kf, sacc[1][ni], 0, 0, 0);
            }
        __builtin_amdgcn_s_setprio(0);
        #pragma unroll
        for (int qs = 0; qs < 2; ++qs)
            #pragma unroll
            for (int ni = 0; ni < 4; ++ni)
                #pragma unroll
                for (int j = 0; j < 4; ++j) {
                    const float p = __expf(sacc[qs][ni][j] * 0.125f);
                    rs[qs][j] += p;
                    const int row = qs*16 + g4*4 + j, key = ni*16 + lo;
                    Pw[row*64 + (((key >> 3) ^ (row & 7))*8) + (key & 7)] = f2b(p);
                }
        asm volatile("" ::: "memory");
        __builtin_amdgcn_s_setprio(1);
        #pragma unroll
        for (int ks = 0; ks < 2; ++ks) {
            bf16x8 vf[4];
            #pragma unroll
            for (int ni = 0; ni < 4; ++ni)
                vf[ni] = *(const bf16x8*)(Vt + vtb[ni] + kt*64 + ks*32 + g4*8);
            #pragma unroll
            for (int qs = 0; qs < 2; ++qs) {
                const int prow = qs*16 + lo;
                const bf16x8 pa = *(const bf16x8*)(Pw + prow*64 + (((ks*4 + g4) ^ (lo & 7))*8));
                #pragma unroll
                for (int ni = 0; ni < 4; ++ni)
                    cacc[qs][ni] = __builtin_amdgcn_mfma_f32_16x16x32_bf16(pa, vf[ni], cacc[qs][ni], 0, 0, 0);
            }
        }
        __builtin_amdgcn_s_setprio(0);
        asm volatile("" ::: "memory");
    }

    // reduce rowsums, write ctx, publish rowsums to LDS (per-wave, no barrier)
    #pragma unroll
    for (int qs = 0; qs < 2; ++qs) {
        #pragma unroll
        for (int j = 0; j < 4; ++j) {
            float r = rs[qs][j];
            r += __shfl_xor(r, 1); r += __shfl_xor(r, 2);
            r += __shfl_xor(r, 4); r += __shfl_xor(r, 8);
            rs[qs][j] = r;
        }
        if (lo == 0) {
            #pragma unroll
            for (int j = 0; j < 4; ++j) Rs[w][qs*16 + g4*4 + j] = rs[qs][j];
        }
        #pragma unroll
        for (int j = 0; j < 4; ++j) {
            const float inv = 1.0f / rs[qs][j];
            #pragma unroll
            for (int ni = 0; ni < 4; ++ni)
                ctxb[(size_t)(b*S_ + qbase + qs*16 + g4*4 + j)*D_ + h*DH_ + ni*16 + lo] =
                    f2b(cacc[qs][ni][j] * inv);
        }
    }
    asm volatile("" ::: "memory");
    const float binv0 = 1.0f / Rs[w][lo];
    const float binv1 = 1.0f / Rs[w][16 + lo];

    // ---------------- phase B: recompute + write normalized attn -------------
    float* arow0 = attn + ((size_t)(b*H_ + h)*S_ + qbase + lo)*S_;
    float* arow1 = arow0 + (size_t)16*S_;
    for (int kt = 0; kt < 32; ++kt) {
        const size_t kbase = (size_t)(b*S_ + kt*64)*D_ + h*DH_;
        f32x4 sacc[2][4];
        #pragma unroll
        for (int qs = 0; qs < 2; ++qs)
            #pragma unroll
            for (int ni = 0; ni < 4; ++ni) sacc[qs][ni] = zero;
        __builtin_amdgcn_s_setprio(1);
        #pragma unroll
        for (int ks = 0; ks < 2; ++ks)
            #pragma unroll
            for (int ni = 0; ni < 4; ++ni) {
                const bf16x8 kf = *(const bf16x8*)(Kh + kbase + (size_t)(ni*16 + lo)*D_ + ks*32 + g4*8);
                sacc[0][ni] = __builtin_amdgcn_mfma_f32_16x16x32_bf16(kf, qf[0][ks], sacc[0][ni], 0, 0, 0);
                sacc[1][ni] = __builtin_amdgcn_mfma_f32_16x16x32_bf16(kf, qf[1][ks], sacc[1][ni], 0, 0, 0);
            }
        __builtin_amdgcn_s_setprio(0);
        #pragma unroll
        for (int ni = 0; ni < 4; ++ni) {
            f32x4 p0, p1;
            p0[0] = __expf(sacc[0][ni][0]*0.125f)*binv0;
            p0[1] = __expf(sacc[0][ni][1]*0.125f)*binv0;
            p0[2] = __expf(sacc[0][ni][2]*0.125f)*binv0;
            p0[3] = __expf(sacc[0][ni][3]*0.125f)*binv0;
            p1[0] = __expf(sacc[1][ni][0]*0.125f)*binv1;
            p1[1] = __expf(sacc[1][ni][1]*0.125f)*binv1;
            p1[2] = __expf(sacc[1][ni][2]*0.125f)*binv1;
            p1[3] = __expf(sacc[1][ni][3]*0.125f)*binv1;
            __builtin_nontemporal_store(p0, (f32x4*)(arow0 + kt*64 + ni*16 + g4*4));
            __builtin_nontemporal_store(p1, (f32x4*)(arow1 + kt*64 + ni*16 + g4*4));
        }
    }
}

// ---------------- output GEMM: out[M][1024] = ctx@Wo + bo (fp32 out) ---------
__global__ __launch_bounds__(256)
void gemm_out(const u16* __restrict__ Ab, const u16* __restrict__ Wt,
              const float* __restrict__ bias, float* __restrict__ Cf)
{
    const int lin = blockIdx.y*64 + blockIdx.x;
    const int cx = lin & 7, idx = lin >> 3;
    const int nx = cx*8 + (idx & 7), ny = idx >> 3;
    const int m0 = nx*128, n0 = ny*128;

    __shared__ u16 AsU[128*64];
    __shared__ u16 BsU[128*64];
    const int t = threadIdx.x;
    const int w = t >> 6, lane = t & 63;
    const int lo = lane & 15, g4 = lane >> 4;
    const int wr = w >> 1, wc = w & 1;
    const int wbase = w*64;

    const f32x4 zero = {0.f, 0.f, 0.f, 0.f};
    f32x4 acc[4][4];
    #pragma unroll
    for (int mi = 0; mi < 4; ++mi)
        #pragma unroll
        for (int ni = 0; ni < 4; ++ni) acc[mi][ni] = zero;

    for (int k0 = 0; k0 < 1024; k0 += 64) {
        __syncthreads();
        #pragma unroll
        for (int c = 0; c < 4; ++c) {
            const int sidx = c*256 + wbase + lane;
            const int row = sidx >> 3;
            const int gblk = (sidx & 7) ^ (row & 7);
            gl_lds16(Ab + (size_t)(m0+row)*D_ + k0 + gblk*8, AsU + (size_t)(c*256 + wbase)*8);
            gl_lds16(Wt + (size_t)(n0+row)*D_ + k0 + gblk*8, BsU + (size_t)(c*256 + wbase)*8);
        }
        __syncthreads();
        #pragma unroll
        for (int ks = 0; ks < 2; ++ks) {
            bf16x8 af[4], bfr[4];
            #pragma unroll
            for (int mi = 0; mi < 4; ++mi) {
                const int row = wr*64 + mi*16 + lo;
                af[mi] = *(const bf16x8*)(AsU + row*64 + (((ks*4+g4) ^ (lo&7))*8));
            }
            #pragma unroll
            for (int ni = 0; ni < 4; ++ni) {
                const int row = wc*64 + ni*16 + lo;
                bfr[ni] = *(const bf16x8*)(BsU + row*64 + (((ks*4+g4) ^ (lo&7))*8));
            }
            #pragma unroll
            for (int mi = 0; mi < 4; ++mi)
                #pragma unroll
                for (int ni = 0; ni < 4; ++ni)
                    acc[mi][ni] = __builtin_amdgcn_mfma_f32_16x16x32_bf16(
                        af[mi], bfr[ni], acc[mi][ni], 0, 0, 0);
        }
    }

    #pragma unroll
    for (int ni = 0; ni < 4; ++ni) {
        const int n = n0 + wc*64 + ni*16 + lo;
        const float bb = bias[n];
        #pragma unroll
        for (int mi = 0; mi < 4; ++mi)
            #pragma unroll
            for (int j = 0; j < 4; ++j) {
                const size_t m = (size_t)(m0 + wr*64 + mi*16 + g4*4 + j);
                Cf[m*D_ + n] = acc[mi][ni][j] + bb;
            }
    }
}

// ----------------------------------------------------------------------------
extern "C" void kernel_launch(void* const* d_in, const int* in_sizes, int n_in,
                              void* d_out, int out_size, void* d_ws, size_t ws_size,
                              hipStream_t stream)
{
    (void)in_sizes; (void)n_in; (void)out_size; (void)ws_size;
    const float* v  = (const float*)d_in[0];
    const float* k  = (const float*)d_in[1];
    const float* q  = (const float*)d_in[2];
    const float* Wq = (const float*)d_in[3];
    const float* bq = (const float*)d_in[4];
    const float* Wk = (const float*)d_in[5];
    const float* bk = (const float*)d_in[6];
    const float* Wv = (const float*)d_in[7];
    const float* bv = (const float*)d_in[8];
    const float* Wo = (const float*)d_in[9];
    const float* bo = (const float*)d_in[10];

    float* out  = (float*)d_out;                  // (B,S,D) fp32
    float* attn = out + (size_t)M_*D_;            // (B,H,S,S) fp32

    u16* qb  = (u16*)d_ws;
    u16* kb  = qb  + (size_t)M_*D_;
    u16* vb  = kb  + (size_t)M_*D_;
    u16* Wqt = vb  + (size_t)M_*D_;
    u16* Wkt = Wqt + (size_t)D_*D_;
    u16* Wvt = Wkt + (size_t)D_*D_;
    u16* Wot = Wvt + (size_t)D_*D_;
    u16* Qhb = Wot + (size_t)D_*D_;
    u16* Khb = Qhb + (size_t)M_*D_;
    u16* Vtb = Khb + (size_t)M_*D_;
    u16* ctxb = qb;                               // reuse (dead after q-proj)

    dim3 b256(256);

    cvt3     <<<dim3(4096, 3),   b256, 0, stream>>>(q, k, v, qb, kb, vb);
    wtrans4  <<<dim3(16, 16, 4), b256, 0, stream>>>(Wq, Wk, Wv, Wo, Wqt, Wkt, Wvt, Wot);
    proj_qkv <<<dim3(64, 8, 3),  b256, 0, stream>>>(qb, kb, vb, Wqt, Wkt, Wvt,
                                                    bq, bk, bv, Qhb, Khb, Vtb);
    attn_fused<<<dim3(16, 16, 4),b256, 0, stream>>>(Qhb, Khb, Vtb, ctxb, attn);
    gemm_out <<<dim3(64, 8),     b256, 0, stream>>>(ctxb, Wot, bo, out);
}

// Round 7
// 508.834 us; speedup vs baseline: 4.3354x; 1.3122x over previous
//
#include <hip/hip_runtime.h>
#include <hip/hip_bf16.h>

#define B_  4
#define S_  2048
#define D_  1024
#define H_  16
#define DH_ 64
#define M_  (B_*S_)   // 8192

typedef short bf16x8 __attribute__((ext_vector_type(8)));   // 8 bf16 = 4 VGPR
typedef float f32x4  __attribute__((ext_vector_type(4)));
typedef unsigned short u16;

__device__ __forceinline__ u16 f2b(float x) {
    union { __hip_bfloat16 h; u16 u; } c; c.h = __float2bfloat16(x); return c.u;
}

// global -> LDS direct (16B per lane). LDS dst is wave-uniform base + lane*16;
// global src is per-lane (pre-swizzle applied there, rule #21/m173).
__device__ __forceinline__ void gl_lds16(const u16* g, u16* l) {
    __builtin_amdgcn_global_load_lds(
        (const __attribute__((address_space(1))) unsigned int*)g,
        (__attribute__((address_space(3))) unsigned int*)l,
        16, 0, 0);
}

// ---------------- fp32 -> bf16 bulk convert, q/k/v in one launch -------------
__global__ __launch_bounds__(256)
void cvt3(const float* __restrict__ q, const float* __restrict__ k,
          const float* __restrict__ v,
          u16* __restrict__ qb, u16* __restrict__ kb, u16* __restrict__ vb)
{
    const float* src = blockIdx.y == 0 ? q : (blockIdx.y == 1 ? k : v);
    u16*         dst = blockIdx.y == 0 ? qb : (blockIdx.y == 1 ? kb : vb);
    const int i = blockIdx.x*256 + threadIdx.x;      // 0..2^20-1 exact
    float4 a = ((const float4*)src)[2*i];
    float4 b = ((const float4*)src)[2*i+1];
    union { u16 u[8]; uint4 v4; } r;
    r.u[0]=f2b(a.x); r.u[1]=f2b(a.y); r.u[2]=f2b(a.z); r.u[3]=f2b(a.w);
    r.u[4]=f2b(b.x); r.u[5]=f2b(b.y); r.u[6]=f2b(b.z); r.u[7]=f2b(b.w);
    ((uint4*)dst)[i] = r.v4;
}

// ---------------- W[k][n] fp32 -> Wt[n][k] bf16, all four in one launch ------
__global__ __launch_bounds__(256)
void wtrans4(const float* __restrict__ Wq, const float* __restrict__ Wk,
             const float* __restrict__ Wv, const float* __restrict__ Wo,
             u16* __restrict__ Wqt, u16* __restrict__ Wkt,
             u16* __restrict__ Wvt, u16* __restrict__ Wot)
{
    const int z = blockIdx.z;
    const float* W  = z==0 ? Wq  : (z==1 ? Wk  : (z==2 ? Wv  : Wo));
    u16*         Wt = z==0 ? Wqt : (z==1 ? Wkt : (z==2 ? Wvt : Wot));
    __shared__ u16 Ts[64][80];
    const int t = threadIdx.x;
    const int k0 = blockIdx.x*64, n0 = blockIdx.y*64;
    const int kr = t >> 4, nc = (t & 15)*4;
    #pragma unroll
    for (int i = 0; i < 4; ++i) {
        const int kk = kr + i*16;
        float4 wv = *(const float4*)(W + (size_t)(k0 + kk)*D_ + n0 + nc);
        Ts[nc+0][kk] = f2b(wv.x); Ts[nc+1][kk] = f2b(wv.y);
        Ts[nc+2][kk] = f2b(wv.z); Ts[nc+3][kk] = f2b(wv.w);
    }
    __syncthreads();
    const int nr = t >> 2, kc = (t & 3)*16;
    u16* dst = Wt + (size_t)(n0 + nr)*D_ + k0 + kc;
    *(uint4*)(dst)     = *(const uint4*)(&Ts[nr][kc]);
    *(uint4*)(dst + 8) = *(const uint4*)(&Ts[nr][kc + 8]);
}

// ---------------- QKV projection GEMM, one launch (z selects) ----------------
__global__ __launch_bounds__(256)
void proj_qkv(const u16* __restrict__ qb, const u16* __restrict__ kb,
              const u16* __restrict__ vb,
              const u16* __restrict__ Wqt, const u16* __restrict__ Wkt,
              const u16* __restrict__ Wvt,
              const float* __restrict__ bq, const float* __restrict__ bk,
              const float* __restrict__ bv,
              u16* __restrict__ Qhb, u16* __restrict__ Khb,
              u16* __restrict__ Vtb)
{
    const int z = blockIdx.z;
    const u16* Ab     = z==0 ? qb  : (z==1 ? kb  : vb);
    const u16* Wt     = z==0 ? Wqt : (z==1 ? Wkt : Wvt);
    const float* bias = z==0 ? bq  : (z==1 ? bk  : bv);

    const int lin = blockIdx.y*64 + blockIdx.x;      // 0..511
    const int cx = lin & 7, idx = lin >> 3;
    const int nx = cx*8 + (idx & 7), ny = idx >> 3;  // bijective
    const int m0 = nx*128, n0 = ny*128;

    __shared__ u16 AsU[128*64];
    __shared__ u16 BsU[128*64];
    const int t = threadIdx.x;
    const int w = t >> 6, lane = t & 63;
    const int lo = lane & 15, g4 = lane >> 4;
    const int wr = w >> 1, wc = w & 1;
    const int wbase = w*64;

    const f32x4 zero = {0.f, 0.f, 0.f, 0.f};
    f32x4 acc[4][4];
    #pragma unroll
    for (int mi = 0; mi < 4; ++mi)
        #pragma unroll
        for (int ni = 0; ni < 4; ++ni) acc[mi][ni] = zero;

    for (int k0 = 0; k0 < 1024; k0 += 64) {
        __syncthreads();
        #pragma unroll
        for (int c = 0; c < 4; ++c) {
            const int sidx = c*256 + wbase + lane;
            const int row = sidx >> 3;
            const int gblk = (sidx & 7) ^ (row & 7);
            gl_lds16(Ab + (size_t)(m0+row)*D_ + k0 + gblk*8, AsU + (size_t)(c*256 + wbase)*8);
            gl_lds16(Wt + (size_t)(n0+row)*D_ + k0 + gblk*8, BsU + (size_t)(c*256 + wbase)*8);
        }
        __syncthreads();
        #pragma unroll
        for (int ks = 0; ks < 2; ++ks) {
            bf16x8 af[4], bfr[4];
            #pragma unroll
            for (int mi = 0; mi < 4; ++mi) {
                const int row = wr*64 + mi*16 + lo;
                af[mi] = *(const bf16x8*)(AsU + row*64 + (((ks*4+g4) ^ (lo&7))*8));
            }
            #pragma unroll
            for (int ni = 0; ni < 4; ++ni) {
                const int row = wc*64 + ni*16 + lo;
                bfr[ni] = *(const bf16x8*)(BsU + row*64 + (((ks*4+g4) ^ (lo&7))*8));
            }
            #pragma unroll
            for (int mi = 0; mi < 4; ++mi)
                #pragma unroll
                for (int ni = 0; ni < 4; ++ni)
                    acc[mi][ni] = __builtin_amdgcn_mfma_f32_16x16x32_bf16(
                        af[mi], bfr[ni], acc[mi][ni], 0, 0, 0);
        }
    }

    if (z < 2) {
        u16* C = z==0 ? Qhb : Khb;
        #pragma unroll
        for (int ni = 0; ni < 4; ++ni) {
            const int n = n0 + wc*64 + ni*16 + lo;
            const float bb = bias[n];
            #pragma unroll
            for (int mi = 0; mi < 4; ++mi)
                #pragma unroll
                for (int j = 0; j < 4; ++j) {
                    const size_t m = (size_t)(m0 + wr*64 + mi*16 + g4*4 + j);
                    C[m*D_ + n] = f2b(acc[mi][ni][j] + bb);
                }
        }
    } else {
        // transposed: Vt[b*D_ + n][s], s = within-batch row
        const int bb_ = m0 >> 11;
        const int sbase = (m0 & 2047) + wr*64;
        #pragma unroll
        for (int ni = 0; ni < 4; ++ni) {
            const int n = n0 + wc*64 + ni*16 + lo;
            const float bv_ = bias[n];
            u16* vrow = Vtb + (size_t)(bb_*D_ + n)*S_ + sbase;
            #pragma unroll
            for (int mi = 0; mi < 4; ++mi) {
                union { u16 u[4]; uint2 v2; } pk;
                #pragma unroll
                for (int j = 0; j < 4; ++j) pk.u[j] = f2b(acc[mi][ni][j] + bv_);
                *(uint2*)(vrow + mi*16 + g4*4) = pk.v2;  // 8B, aligned
            }
        }
    }
}

// ---------------- pass 1: QK^T + exp + rowsum only ---------------------------
// Block = 128 q rows (4 waves x 32q), one (b,h). No LDS, no PV -> low VGPR,
// high occupancy. XCD swizzle for K L2 residency.
__global__ __launch_bounds__(256)
void attn_sums(const u16* __restrict__ Qh, const u16* __restrict__ Kh,
               float* __restrict__ rsum)
{
    const int t = threadIdx.x, w = t >> 6, lane = t & 63;
    const int lo = lane & 15, g4 = lane >> 4;

    const int lin = (blockIdx.z*16 + blockIdx.y)*16 + blockIdx.x;  // 0..1023
    const int cx = lin & 7, idx = lin >> 3;
    const int nl = cx*128 + idx;
    const int qb_ = nl & 15, bh = nl >> 4;
    const int h = bh & 15, b = bh >> 4;
    const int qbase = qb_*128 + w*32;

    bf16x8 qf[2][2];
    #pragma unroll
    for (int qs = 0; qs < 2; ++qs)
        #pragma unroll
        for (int ks = 0; ks < 2; ++ks)
            qf[qs][ks] = *(const bf16x8*)(Qh + (size_t)(b*S_ + qbase + qs*16 + lo)*D_ + h*DH_ + ks*32 + g4*8);

    const f32x4 zero = {0.f, 0.f, 0.f, 0.f};
    float rs[2][4] = {};

    for (int kt = 0; kt < 32; ++kt) {
        const size_t kbase = (size_t)(b*S_ + kt*64)*D_ + h*DH_;
        f32x4 sacc[2][4];
        #pragma unroll
        for (int qs = 0; qs < 2; ++qs)
            #pragma unroll
            for (int ni = 0; ni < 4; ++ni) sacc[qs][ni] = zero;
        __builtin_amdgcn_s_setprio(1);
        #pragma unroll
        for (int ks = 0; ks < 2; ++ks)
            #pragma unroll
            for (int ni = 0; ni < 4; ++ni) {
                const bf16x8 kf = *(const bf16x8*)(Kh + kbase + (size_t)(ni*16 + lo)*D_ + ks*32 + g4*8);
                sacc[0][ni] = __builtin_amdgcn_mfma_f32_16x16x32_bf16(qf[0][ks], kf, sacc[0][ni], 0, 0, 0);
                sacc[1][ni] = __builtin_amdgcn_mfma_f32_16x16x32_bf16(qf[1][ks], kf, sacc[1][ni], 0, 0, 0);
            }
        __builtin_amdgcn_s_setprio(0);
        #pragma unroll
        for (int qs = 0; qs < 2; ++qs)
            #pragma unroll
            for (int ni = 0; ni < 4; ++ni)
                #pragma unroll
                for (int j = 0; j < 4; ++j)
                    rs[qs][j] += __expf(sacc[qs][ni][j] * 0.125f);
    }

    const size_t rb = (size_t)(b*H_ + h)*S_ + qbase;
    #pragma unroll
    for (int qs = 0; qs < 2; ++qs) {
        #pragma unroll
        for (int j = 0; j < 4; ++j) {
            float r = rs[qs][j];
            r += __shfl_xor(r, 1); r += __shfl_xor(r, 2);
            r += __shfl_xor(r, 4); r += __shfl_xor(r, 8);
            rs[qs][j] = r;
        }
        if (lo == 0) {
            #pragma unroll
            for (int j = 0; j < 4; ++j) rsum[rb + qs*16 + g4*4 + j] = rs[qs][j];
        }
    }
}

// ---------------- pass 2: QK^T + normalize-store attn + PV + ctx -------------
// Same QK^T arithmetic as pass 1 (bitwise-identical exp). Per kt the 1 GB attn
// write interleaves with PV MFMA -> HBM write stream overlaps compute.
__global__ __launch_bounds__(256)
void attn_out(const u16* __restrict__ Qh, const u16* __restrict__ Kh,
              const u16* __restrict__ Vt, const float* __restrict__ rsum,
              u16* __restrict__ ctxb, float* __restrict__ attn)
{
    __shared__ u16 Plds[4*2048];    // per-wave 32q x 64key, XOR-swizzled
    const int t = threadIdx.x, w = t >> 6, lane = t & 63;
    const int lo = lane & 15, g4 = lane >> 4;

    const int lin = (blockIdx.z*16 + blockIdx.y)*16 + blockIdx.x;  // 0..1023
    const int cx = lin & 7, idx = lin >> 3;
    const int nl = cx*128 + idx;
    const int qb_ = nl & 15, bh = nl >> 4;
    const int h = bh & 15, b = bh >> 4;
    const int qbase = qb_*128 + w*32;
    u16* Pw = Plds + w*2048;

    bf16x8 qf[2][2];
    #pragma unroll
    for (int qs = 0; qs < 2; ++qs)
        #pragma unroll
        for (int ks = 0; ks < 2; ++ks)
            qf[qs][ks] = *(const bf16x8*)(Qh + (size_t)(b*S_ + qbase + qs*16 + lo)*D_ + h*DH_ + ks*32 + g4*8);

    const size_t rb = (size_t)(b*H_ + h)*S_ + qbase;
    float invp[2][4];
    #pragma unroll
    for (int qs = 0; qs < 2; ++qs)
        #pragma unroll
        for (int j = 0; j < 4; ++j)
            invp[qs][j] = 1.0f / rsum[rb + qs*16 + g4*4 + j];

    size_t vtb[4];
    #pragma unroll
    for (int ni = 0; ni < 4; ++ni)
        vtb[ni] = (size_t)(b*D_ + h*DH_ + ni*16 + lo)*S_;

    // attn row base for this lane's q rows: q = qbase + qs*16 + g4*4 + j
    float* abase = attn + ((size_t)(b*H_ + h)*S_ + qbase + g4*4)*S_;

    const f32x4 zero = {0.f, 0.f, 0.f, 0.f};
    f32x4 cacc[2][4];
    #pragma unroll
    for (int qs = 0; qs < 2; ++qs)
        #pragma unroll
        for (int ni = 0; ni < 4; ++ni) cacc[qs][ni] = zero;

    for (int kt = 0; kt < 32; ++kt) {
        const size_t kbase = (size_t)(b*S_ + kt*64)*D_ + h*DH_;
        f32x4 sacc[2][4];
        #pragma unroll
        for (int qs = 0; qs < 2; ++qs)
            #pragma unroll
            for (int ni = 0; ni < 4; ++ni) sacc[qs][ni] = zero;
        __builtin_amdgcn_s_setprio(1);
        #pragma unroll
        for (int ks = 0; ks < 2; ++ks)
            #pragma unroll
            for (int ni = 0; ni < 4; ++ni) {
                const bf16x8 kf = *(const bf16x8*)(Kh + kbase + (size_t)(ni*16 + lo)*D_ + ks*32 + g4*8);
                sacc[0][ni] = __builtin_amdgcn_mfma_f32_16x16x32_bf16(qf[0][ks], kf, sacc[0][ni], 0, 0, 0);
                sacc[1][ni] = __builtin_amdgcn_mfma_f32_16x16x32_bf16(qf[1][ks], kf, sacc[1][ni], 0, 0, 0);
            }
        __builtin_amdgcn_s_setprio(0);
        // exp -> P LDS (unnormalized) + nt-store normalized attn
        #pragma unroll
        for (int qs = 0; qs < 2; ++qs)
            #pragma unroll
            for (int ni = 0; ni < 4; ++ni)
                #pragma unroll
                for (int j = 0; j < 4; ++j) {
                    const float p = __expf(sacc[qs][ni][j] * 0.125f);
                    const int row = qs*16 + g4*4 + j, key = ni*16 + lo;
                    Pw[row*64 + (((key >> 3) ^ (row & 7))*8) + (key & 7)] = f2b(p);
                    __builtin_nontemporal_store(p * invp[qs][j],
                        abase + ((size_t)(qs*16 + j))*S_ + kt*64 + key);
                }
        asm volatile("" ::: "memory");
        __builtin_amdgcn_s_setprio(1);
        #pragma unroll
        for (int ks = 0; ks < 2; ++ks) {
            bf16x8 vf[4];
            #pragma unroll
            for (int ni = 0; ni < 4; ++ni)
                vf[ni] = *(const bf16x8*)(Vt + vtb[ni] + kt*64 + ks*32 + g4*8);
            #pragma unroll
            for (int qs = 0; qs < 2; ++qs) {
                const int prow = qs*16 + lo;
                const bf16x8 pa = *(const bf16x8*)(Pw + prow*64 + (((ks*4 + g4) ^ (lo & 7))*8));
                #pragma unroll
                for (int ni = 0; ni < 4; ++ni)
                    cacc[qs][ni] = __builtin_amdgcn_mfma_f32_16x16x32_bf16(pa, vf[ni], cacc[qs][ni], 0, 0, 0);
            }
        }
        __builtin_amdgcn_s_setprio(0);
        asm volatile("" ::: "memory");
    }

    #pragma unroll
    for (int qs = 0; qs < 2; ++qs)
        #pragma unroll
        for (int j = 0; j < 4; ++j) {
            const float inv = invp[qs][j];
            #pragma unroll
            for (int ni = 0; ni < 4; ++ni)
                ctxb[(size_t)(b*S_ + qbase + qs*16 + g4*4 + j)*D_ + h*DH_ + ni*16 + lo] =
                    f2b(cacc[qs][ni][j] * inv);
        }
}

// ---------------- output GEMM: out[M][1024] = ctx@Wo + bo (fp32 out) ---------
__global__ __launch_bounds__(256)
void gemm_out(const u16* __restrict__ Ab, const u16* __restrict__ Wt,
              const float* __restrict__ bias, float* __restrict__ Cf)
{
    const int lin = blockIdx.y*64 + blockIdx.x;
    const int cx = lin & 7, idx = lin >> 3;
    const int nx = cx*8 + (idx & 7), ny = idx >> 3;
    const int m0 = nx*128, n0 = ny*128;

    __shared__ u16 AsU[128*64];
    __shared__ u16 BsU[128*64];
    const int t = threadIdx.x;
    const int w = t >> 6, lane = t & 63;
    const int lo = lane & 15, g4 = lane >> 4;
    const int wr = w >> 1, wc = w & 1;
    const int wbase = w*64;

    const f32x4 zero = {0.f, 0.f, 0.f, 0.f};
    f32x4 acc[4][4];
    #pragma unroll
    for (int mi = 0; mi < 4; ++mi)
        #pragma unroll
        for (int ni = 0; ni < 4; ++ni) acc[mi][ni] = zero;

    for (int k0 = 0; k0 < 1024; k0 += 64) {
        __syncthreads();
        #pragma unroll
        for (int c = 0; c < 4; ++c) {
            const int sidx = c*256 + wbase + lane;
            const int row = sidx >> 3;
            const int gblk = (sidx & 7) ^ (row & 7);
            gl_lds16(Ab + (size_t)(m0+row)*D_ + k0 + gblk*8, AsU + (size_t)(c*256 + wbase)*8);
            gl_lds16(Wt + (size_t)(n0+row)*D_ + k0 + gblk*8, BsU + (size_t)(c*256 + wbase)*8);
        }
        __syncthreads();
        #pragma unroll
        for (int ks = 0; ks < 2; ++ks) {
            bf16x8 af[4], bfr[4];
            #pragma unroll
            for (int mi = 0; mi < 4; ++mi) {
                const int row = wr*64 + mi*16 + lo;
                af[mi] = *(const bf16x8*)(AsU + row*64 + (((ks*4+g4) ^ (lo&7))*8));
            }
            #pragma unroll
            for (int ni = 0; ni < 4; ++ni) {
                const int row = wc*64 + ni*16 + lo;
                bfr[ni] = *(const bf16x8*)(BsU + row*64 + (((ks*4+g4) ^ (lo&7))*8));
            }
            #pragma unroll
            for (int mi = 0; mi < 4; ++mi)
                #pragma unroll
                for (int ni = 0; ni < 4; ++ni)
                    acc[mi][ni] = __builtin_amdgcn_mfma_f32_16x16x32_bf16(
                        af[mi], bfr[ni], acc[mi][ni], 0, 0, 0);
        }
    }

    #pragma unroll
    for (int ni = 0; ni < 4; ++ni) {
        const int n = n0 + wc*64 + ni*16 + lo;
        const float bb = bias[n];
        #pragma unroll
        for (int mi = 0; mi < 4; ++mi)
            #pragma unroll
            for (int j = 0; j < 4; ++j) {
                const size_t m = (size_t)(m0 + wr*64 + mi*16 + g4*4 + j);
                Cf[m*D_ + n] = acc[mi][ni][j] + bb;
            }
    }
}

// ----------------------------------------------------------------------------
extern "C" void kernel_launch(void* const* d_in, const int* in_sizes, int n_in,
                              void* d_out, int out_size, void* d_ws, size_t ws_size,
                              hipStream_t stream)
{
    (void)in_sizes; (void)n_in; (void)out_size; (void)ws_size;
    const float* v  = (const float*)d_in[0];
    const float* k  = (const float*)d_in[1];
    const float* q  = (const float*)d_in[2];
    const float* Wq = (const float*)d_in[3];
    const float* bq = (const float*)d_in[4];
    const float* Wk = (const float*)d_in[5];
    const float* bk = (const float*)d_in[6];
    const float* Wv = (const float*)d_in[7];
    const float* bv = (const float*)d_in[8];
    const float* Wo = (const float*)d_in[9];
    const float* bo = (const float*)d_in[10];

    float* out  = (float*)d_out;                  // (B,S,D) fp32
    float* attn = out + (size_t)M_*D_;            // (B,H,S,S) fp32

    u16* qb  = (u16*)d_ws;
    u16* kb  = qb  + (size_t)M_*D_;
    u16* vb  = kb  + (size_t)M_*D_;
    u16* Wqt = vb  + (size_t)M_*D_;
    u16* Wkt = Wqt + (size_t)D_*D_;
    u16* Wvt = Wkt + (size_t)D_*D_;
    u16* Wot = Wvt + (size_t)D_*D_;
    u16* Qhb = Wot + (size_t)D_*D_;
    u16* Khb = Qhb + (size_t)M_*D_;
    u16* Vtb = Khb + (size_t)M_*D_;
    u16* ctxb = qb;                               // reuse (dead after q-proj)
    float* rsum = (float*)vb;                     // reuse (dead after v-proj)

    dim3 b256(256);

    cvt3     <<<dim3(4096, 3),   b256, 0, stream>>>(q, k, v, qb, kb, vb);
    wtrans4  <<<dim3(16, 16, 4), b256, 0, stream>>>(Wq, Wk, Wv, Wo, Wqt, Wkt, Wvt, Wot);
    proj_qkv <<<dim3(64, 8, 3),  b256, 0, stream>>>(qb, kb, vb, Wqt, Wkt, Wvt,
                                                    bq, bk, bv, Qhb, Khb, Vtb);
    attn_sums<<<dim3(16, 16, 4), b256, 0, stream>>>(Qhb, Khb, rsum);
    attn_out <<<dim3(16, 16, 4), b256, 0, stream>>>(Qhb, Khb, Vtb, rsum, ctxb, attn);
    gemm_out <<<dim3(64, 8),     b256, 0, stream>>>(ctxb, Wot, bo, out);
}